// Round 6
// baseline (610.516 us; speedup 1.0000x reference)
//
#include <hip/hip_runtime.h>
#include <hip/hip_fp16.h>
#include <math.h>

#define HEADS 4
#define OUT_F 32
#define HF 128      // HEADS*OUT_F
#define IN_F 64
#define EDGE_F 16

typedef int   v4i __attribute__((ext_vector_type(4)));
typedef float v4f __attribute__((ext_vector_type(4)));
typedef float v2f __attribute__((ext_vector_type(2)));

// ---------- node projection: xp (f16), residual->out, a_s/a_t ----------
__global__ __launch_bounds__(128) void k_node(
    const float* __restrict__ x, const float* __restrict__ W_lin,
    const float* __restrict__ W_res, const float* __restrict__ bias,
    const float* __restrict__ w_s, const float* __restrict__ w_t,
    const float* __restrict__ b_s, const float* __restrict__ b_t,
    __half* __restrict__ xp, float* __restrict__ a_s, float* __restrict__ a_t,
    float* __restrict__ out, int N_) {
  __shared__ float4 sx[8][16];
  int c = threadIdx.x;  // output feature 0..127
  float4 wl[16], wr[16];
  const float4* Wl4 = (const float4*)(W_lin + c * IN_F);
  const float4* Wr4 = (const float4*)(W_res + c * IN_F);
#pragma unroll
  for (int k = 0; k < 16; k++) { wl[k] = Wl4[k]; wr[k] = Wr4[k]; }
  float wsl = w_s[c & 31], wtl = w_t[c & 31];
  float bsv = b_s[0], btv = b_t[0], bv = bias[c];
  int nstart = blockIdx.x * 16;  // 16 nodes/block: 2x grid of round 5 for occupancy
  for (int tile = 0; tile < 2; tile++) {
    int tbase = nstart + tile * 8;
    {
      int r = c >> 4, q = c & 15;
      int nn = tbase + r;
      sx[r][q] = (nn < N_) ? ((const float4*)(x + (size_t)nn * IN_F))[q]
                           : make_float4(0.f, 0.f, 0.f, 0.f);
    }
    __syncthreads();
    for (int ni = 0; ni < 8; ni++) {
      int n = tbase + ni;
      if (n >= N_) break;  // uniform across block
      float acc = 0.f, accr = 0.f;
#pragma unroll
      for (int k = 0; k < 16; k++) {
        float4 xv = sx[ni][k];
        acc  += xv.x * wl[k].x + xv.y * wl[k].y + xv.z * wl[k].z + xv.w * wl[k].w;
        accr += xv.x * wr[k].x + xv.y * wr[k].y + xv.z * wr[k].z + xv.w * wr[k].w;
      }
      xp[(size_t)n * HF + c] = __float2half(acc);
      out[(size_t)n * HF + c] = accr + bv;
      float vs = acc * wsl, vt = acc * wtl;
#pragma unroll
      for (int d = 16; d > 0; d >>= 1) {
        vs += __shfl_down(vs, d, 32);
        vt += __shfl_down(vt, d, 32);
      }
      if ((c & 31) == 0) {
        a_s[n * 4 + (c >> 5)] = vs + bsv;
        a_t[n * 4 + (c >> 5)] = vt + btv;
      }
    }
    __syncthreads();
  }
}

// ---------- dst histogram: max thread count, one atomic each ----------
__global__ __launch_bounds__(256) void k_count(const int* __restrict__ ei,
                                               int* __restrict__ count, int E_) {
  int e = blockIdx.x * 256 + threadIdx.x;
  if (e < E_) atomicAdd(count + ei[E_ + e], 1);
}

// ---------- single-block exclusive scan of count[n] -> offs, cursor ----------
__global__ __launch_bounds__(1024) void k_scan(const int* __restrict__ count,
                                               int* __restrict__ offs,
                                               int* __restrict__ cursor, int n) {
  __shared__ int wsum[16];
  int t = threadIdx.x;
  int per = (n + 1023) >> 10;
  int base = t * per;
  int s = 0;
  for (int i = 0; i < per; i++) {
    int idx = base + i;
    if (idx < n) s += count[idx];
  }
  int lane = t & 63, wv = t >> 6;
  int incl = s;
#pragma unroll
  for (int d = 1; d < 64; d <<= 1) {
    int v = __shfl_up(incl, d, 64);
    if (lane >= d) incl += v;
  }
  if (lane == 63) wsum[wv] = incl;
  __syncthreads();
  int wadd = 0;
  for (int w = 0; w < wv; w++) wadd += wsum[w];
  int run = wadd + incl - s;  // exclusive prefix of this thread's first element
  for (int i = 0; i < per; i++) {
    int idx = base + i;
    if (idx < n) {
      offs[idx] = run;
      cursor[idx] = run;
      run += count[idx];
    }
  }
}

// ---------- per-edge: inline fold, EARLY cursor atomic, exp logits, place ----------
__global__ __launch_bounds__(256) void k_edge_sort(
    const int* __restrict__ ei, const float* __restrict__ ea,
    const float* __restrict__ W_edge, const float* __restrict__ w_e,
    const float* __restrict__ b_e,
    const float* __restrict__ a_s, const float* __restrict__ a_t,
    int* __restrict__ cursor, v4i* __restrict__ pay, int E_) {
  __shared__ float sv[64];
  {
    int t = threadIdx.x;
    if (t < 64) {  // fold W_edge (128x16) with w_e -> v_e[4][16], from L2
      int h = t >> 4, cc = t & 15;
      float se = 0.f;
#pragma unroll
      for (int f = 0; f < 32; f++) se += W_edge[(h * 32 + f) * 16 + cc] * w_e[f];
      sv[t] = se;
    }
  }
  __syncthreads();
  int e = blockIdx.x * 256 + threadIdx.x;
  if (e >= E_) return;
  int src = ei[e], dst = ei[E_ + e];
  // issue the cursor atomic FIRST: pos is consumed only by the final store,
  // so its ~900-cycle round trip overlaps the entire logit computation below.
  int pos = atomicAdd(cursor + dst, 1);
  float bev = b_e[0];
  const v4f* ea4 = (const v4f*)(ea + (size_t)e * EDGE_F);
  v4f e0 = __builtin_nontemporal_load(ea4 + 0);   // streamed: don't pollute L2
  v4f e1 = __builtin_nontemporal_load(ea4 + 1);
  v4f e2 = __builtin_nontemporal_load(ea4 + 2);
  v4f e3 = __builtin_nontemporal_load(ea4 + 3);
  float4 as4 = *(const float4*)(a_s + src * 4);
  float4 at4 = *(const float4*)(a_t + dst * 4);
  float asv[4] = {as4.x, as4.y, as4.z, as4.w};
  float atv[4] = {at4.x, at4.y, at4.z, at4.w};
  float res[4];
#pragma unroll
  for (int h = 0; h < 4; h++) {
    const float* v = sv + h * 16;
    float ae =
        e0.x * v[0]  + e0.y * v[1]  + e0.z * v[2]  + e0.w * v[3]
      + e1.x * v[4]  + e1.y * v[5]  + e1.z * v[6]  + e1.w * v[7]
      + e2.x * v[8]  + e2.y * v[9]  + e2.z * v[10] + e2.w * v[11]
      + e3.x * v[12] + e3.y * v[13] + e3.z * v[14] + e3.w * v[15];
    float al = asv[h] + atv[h] + ae + bev;
    al = al >= 0.f ? al : 0.2f * al;
    res[h] = __expf(al);  // shift-free softmax: |alpha| is O(1)
  }
  __half2 h01 = __floats2half2_rn(res[0], res[1]);
  __half2 h23 = __floats2half2_rn(res[2], res[3]);
  v4i pk;
  pk.x = src;
  pk.y = *(int*)&h01;
  pk.z = *(int*)&h23;
  pk.w = 0;
  __builtin_nontemporal_store(pk, pay + pos);  // random 16B: skip L2 retention
}

// ---------- gather: one wave per dst node, segment-sum, softmax-divide ----------
__global__ __launch_bounds__(256) void k_gather(
    const int* __restrict__ offs, const int* __restrict__ count,
    const v4i* __restrict__ pay, const __half* __restrict__ xp,
    float* __restrict__ out, int N_) {
  int wid = threadIdx.x >> 6, lane = threadIdx.x & 63;
  int n = blockIdx.x * 4 + wid;
  if (n >= N_) return;
  int start = offs[n], len = count[n];
  if (len == 0) return;  // out keeps residual
  int h = lane >> 4;  // features 2*lane, 2*lane+1 -> head (2*lane)>>5 = lane>>4
  float2 acc = make_float2(0.f, 0.f);
  float se = 0.f;
#pragma unroll 8
  for (int i = 0; i < len; i++) {
    v4i p = __builtin_nontemporal_load(pay + start + i);  // uniform -> broadcast
    unsigned hw = (h < 2) ? (unsigned)p.y : (unsigned)p.z;
    unsigned bits = (h & 1) ? (hw >> 16) : (hw & 0xffffu);
    float ev = __half2float(__ushort_as_half((unsigned short)bits));
    const __half2* xr = (const __half2*)(xp + (size_t)p.x * HF);
    float2 xv = __half22float2(xr[lane]);  // random row: keep in L2
    acc.x += ev * xv.x;
    acc.y += ev * xv.y;
    se += ev;
  }
  float r = 1.f / se;
  size_t oi = (size_t)n * 64 + lane;
  v2f o = __builtin_nontemporal_load((const v2f*)out + oi);
  o.x += acc.x * r;
  o.y += acc.y * r;
  __builtin_nontemporal_store(o, (v2f*)out + oi);
}

extern "C" void kernel_launch(void* const* d_in, const int* in_sizes, int n_in,
                              void* d_out, int out_size, void* d_ws, size_t ws_size,
                              hipStream_t stream) {
  const float* x      = (const float*)d_in[0];
  const int*   ei     = (const int*)  d_in[1];
  const float* ea     = (const float*)d_in[2];
  const float* W_lin  = (const float*)d_in[3];
  const float* w_s    = (const float*)d_in[4];
  const float* b_s    = (const float*)d_in[5];
  const float* w_t    = (const float*)d_in[6];
  const float* b_t    = (const float*)d_in[7];
  const float* W_edge = (const float*)d_in[8];
  const float* w_e    = (const float*)d_in[9];
  const float* b_e    = (const float*)d_in[10];
  const float* W_res  = (const float*)d_in[11];
  const float* bias   = (const float*)d_in[12];
  int N_ = in_sizes[0] / IN_F;
  int E_ = in_sizes[1] / 2;
  float* out = (float*)d_out;

  // ws layout (~39.3 MB; 47.0 MB passed in round 3/4):
  // xp[N*128] f16 | pay[E] int4 | a_s[N*4] f32 | a_t[N*4] f32 |
  // count[N] | offs[N] | cursor[N]
  __half* xp    = (__half*)d_ws;
  v4i*    pay   = (v4i*)(xp + (size_t)N_ * HF);
  float*  a_s   = (float*)(pay + E_);
  float*  a_t   = a_s + (size_t)N_ * 4;
  int*    count = (int*)(a_t + (size_t)N_ * 4);
  int*    offs  = count + N_;
  int*    cursor= offs + N_;

  hipMemsetAsync(count, 0, (size_t)N_ * sizeof(int), stream);
  k_node<<<(N_ + 15) / 16, 128, 0, stream>>>(
      x, W_lin, W_res, bias, w_s, w_t, b_s, b_t, xp, a_s, a_t, out, N_);
  k_count<<<(E_ + 255) / 256, 256, 0, stream>>>(ei, count, E_);
  k_scan<<<1, 1024, 0, stream>>>(count, offs, cursor, N_);
  k_edge_sort<<<(E_ + 255) / 256, 256, 0, stream>>>(
      ei, ea, W_edge, w_e, b_e, a_s, a_t, cursor, pay, E_);
  k_gather<<<(N_ + 3) / 4, 256, 0, stream>>>(offs, count, pay, xp, out, N_);
}

// Round 7
// 463.703 us; speedup vs baseline: 1.3166x; 1.3166x over previous
//
#include <hip/hip_runtime.h>
#include <hip/hip_fp16.h>
#include <math.h>

#define HEADS 4
#define OUT_F 32
#define HF 128      // HEADS*OUT_F
#define IN_F 64
#define EDGE_F 16

typedef int   v4i __attribute__((ext_vector_type(4)));
typedef float v4f __attribute__((ext_vector_type(4)));
typedef float v2f __attribute__((ext_vector_type(2)));

// ---------- heterogeneous grid: node projection blocks + dst-histogram blocks ----------
// blocks [0, NB): project 32 nodes each (xp f16, residual->out, a_s/a_t)
// blocks [NB, NB+CB): histogram of dst with one atomic per thread (full 1.6M threads,
//   co-scheduled with projection -> atomic latency hides under FMA)  [R5 failed because
//   the fused histogram inherited a small grid; this keeps the big grid]
__global__ __launch_bounds__(128) void k_node_count(
    const float* __restrict__ x, const float* __restrict__ W_lin,
    const float* __restrict__ W_res, const float* __restrict__ bias,
    const float* __restrict__ w_s, const float* __restrict__ w_t,
    const float* __restrict__ b_s, const float* __restrict__ b_t,
    const int* __restrict__ ei,
    __half* __restrict__ xp, float* __restrict__ a_s, float* __restrict__ a_t,
    float* __restrict__ out, int* __restrict__ count, int N_, int E_, int NB) {
  if (blockIdx.x >= NB) {  // histogram block
    int e = (blockIdx.x - NB) * 128 + threadIdx.x;
    if (e < E_) atomicAdd(count + ei[E_ + e], 1);
    return;
  }
  __shared__ float4 sx[8][16];
  int c = threadIdx.x;  // output feature 0..127
  float4 wl[16], wr[16];
  const float4* Wl4 = (const float4*)(W_lin + c * IN_F);
  const float4* Wr4 = (const float4*)(W_res + c * IN_F);
#pragma unroll
  for (int k = 0; k < 16; k++) { wl[k] = Wl4[k]; wr[k] = Wr4[k]; }
  float wsl = w_s[c & 31], wtl = w_t[c & 31];
  float bsv = b_s[0], btv = b_t[0], bv = bias[c];
  int nstart = blockIdx.x * 32;
  for (int tile = 0; tile < 4; tile++) {
    int tbase = nstart + tile * 8;
    {
      int r = c >> 4, q = c & 15;
      int nn = tbase + r;
      sx[r][q] = (nn < N_) ? ((const float4*)(x + (size_t)nn * IN_F))[q]
                           : make_float4(0.f, 0.f, 0.f, 0.f);
    }
    __syncthreads();
    for (int ni = 0; ni < 8; ni++) {
      int n = tbase + ni;
      if (n >= N_) break;  // uniform across block
      float acc = 0.f, accr = 0.f;
#pragma unroll
      for (int k = 0; k < 16; k++) {
        float4 xv = sx[ni][k];
        acc  += xv.x * wl[k].x + xv.y * wl[k].y + xv.z * wl[k].z + xv.w * wl[k].w;
        accr += xv.x * wr[k].x + xv.y * wr[k].y + xv.z * wr[k].z + xv.w * wr[k].w;
      }
      xp[(size_t)n * HF + c] = __float2half(acc);
      out[(size_t)n * HF + c] = accr + bv;
      float vs = acc * wsl, vt = acc * wtl;
#pragma unroll
      for (int d = 16; d > 0; d >>= 1) {
        vs += __shfl_down(vs, d, 32);
        vt += __shfl_down(vt, d, 32);
      }
      if ((c & 31) == 0) {
        a_s[n * 4 + (c >> 5)] = vs + bsv;
        a_t[n * 4 + (c >> 5)] = vt + btv;
      }
    }
    __syncthreads();
  }
}

// ---------- 3-phase exclusive scan (multi-block; the 1-block version cost 126 us) ----------
__global__ __launch_bounds__(256) void k_scan1(const int* __restrict__ count,
                                               int* __restrict__ offs,
                                               int* __restrict__ bsum, int n) {
  __shared__ int swv[4];
  int t = threadIdx.x;
  int base = blockIdx.x * 1024 + t * 4;
  int c0 = (base + 0 < n) ? count[base + 0] : 0;
  int c1 = (base + 1 < n) ? count[base + 1] : 0;
  int c2 = (base + 2 < n) ? count[base + 2] : 0;
  int c3 = (base + 3 < n) ? count[base + 3] : 0;
  int s = c0 + c1 + c2 + c3;
  int lane = t & 63, wid = t >> 6;
  int incl = s;
#pragma unroll
  for (int d = 1; d < 64; d <<= 1) {
    int v = __shfl_up(incl, d, 64);
    if (lane >= d) incl += v;
  }
  if (lane == 63) swv[wid] = incl;
  __syncthreads();
  int wadd = 0;
  for (int w = 0; w < wid; w++) wadd += swv[w];
  int excl = wadd + incl - s;
  if (base + 0 < n) offs[base + 0] = excl;
  if (base + 1 < n) offs[base + 1] = excl + c0;
  if (base + 2 < n) offs[base + 2] = excl + c0 + c1;
  if (base + 3 < n) offs[base + 3] = excl + c0 + c1 + c2;
  if (t == 255) bsum[blockIdx.x] = wadd + incl;
}

__global__ void k_scan2(int* __restrict__ bsum, int nb) {  // nb <= 64
  int t = threadIdx.x;  // 64 threads
  int v = (t < nb) ? bsum[t] : 0;
  int incl = v;
#pragma unroll
  for (int d = 1; d < 64; d <<= 1) {
    int u = __shfl_up(incl, d, 64);
    if (t >= d) incl += u;
  }
  if (t < nb) bsum[t] = incl - v;  // exclusive
}

__global__ __launch_bounds__(256) void k_scan3(int* __restrict__ offs,
                                               const int* __restrict__ bsum,
                                               int* __restrict__ cursor, int n) {
  int base = blockIdx.x * 1024 + threadIdx.x * 4;
  int add = bsum[blockIdx.x];
#pragma unroll
  for (int q = 0; q < 4; q++) {
    int i = base + q;
    if (i < n) {
      int v = offs[i] + add;
      offs[i] = v;
      cursor[i] = v;
    }
  }
}

// ---------- per-edge: inline fold, early cursor atomic, exp logits, place ----------
__global__ __launch_bounds__(256) void k_edge_sort(
    const int* __restrict__ ei, const float* __restrict__ ea,
    const float* __restrict__ W_edge, const float* __restrict__ w_e,
    const float* __restrict__ b_e,
    const float* __restrict__ a_s, const float* __restrict__ a_t,
    int* __restrict__ cursor, v4i* __restrict__ pay, int E_) {
  __shared__ float sv[64];
  {
    int t = threadIdx.x;
    if (t < 64) {  // fold W_edge (128x16) with w_e -> v_e[4][16], from L2
      int h = t >> 4, cc = t & 15;
      float se = 0.f;
#pragma unroll
      for (int f = 0; f < 32; f++) se += W_edge[(h * 32 + f) * 16 + cc] * w_e[f];
      sv[t] = se;
    }
  }
  __syncthreads();
  int e = blockIdx.x * 256 + threadIdx.x;
  if (e >= E_) return;
  int src = ei[e], dst = ei[E_ + e];
  // early atomic: pos consumed only by the final store -> latency overlaps logit math
  int pos = atomicAdd(cursor + dst, 1);
  float bev = b_e[0];
  const v4f* ea4 = (const v4f*)(ea + (size_t)e * EDGE_F);
  v4f e0 = __builtin_nontemporal_load(ea4 + 0);   // streamed: don't pollute L2
  v4f e1 = __builtin_nontemporal_load(ea4 + 1);
  v4f e2 = __builtin_nontemporal_load(ea4 + 2);
  v4f e3 = __builtin_nontemporal_load(ea4 + 3);
  float4 as4 = *(const float4*)(a_s + src * 4);
  float4 at4 = *(const float4*)(a_t + dst * 4);
  float asv[4] = {as4.x, as4.y, as4.z, as4.w};
  float atv[4] = {at4.x, at4.y, at4.z, at4.w};
  float res[4];
#pragma unroll
  for (int h = 0; h < 4; h++) {
    const float* v = sv + h * 16;
    float ae =
        e0.x * v[0]  + e0.y * v[1]  + e0.z * v[2]  + e0.w * v[3]
      + e1.x * v[4]  + e1.y * v[5]  + e1.z * v[6]  + e1.w * v[7]
      + e2.x * v[8]  + e2.y * v[9]  + e2.z * v[10] + e2.w * v[11]
      + e3.x * v[12] + e3.y * v[13] + e3.z * v[14] + e3.w * v[15];
    float al = asv[h] + atv[h] + ae + bev;
    al = al >= 0.f ? al : 0.2f * al;
    res[h] = __expf(al);  // shift-free softmax: |alpha| is O(1)
  }
  __half2 h01 = __floats2half2_rn(res[0], res[1]);
  __half2 h23 = __floats2half2_rn(res[2], res[3]);
  v4i pk;
  pk.x = src;
  pk.y = *(int*)&h01;
  pk.z = *(int*)&h23;
  pk.w = 0;
  __builtin_nontemporal_store(pk, pay + pos);  // random 16B: skip L2 retention
}

// ---------- gather: one wave per dst node, segment-sum, softmax-divide ----------
__global__ __launch_bounds__(256) void k_gather(
    const int* __restrict__ offs, const int* __restrict__ count,
    const v4i* __restrict__ pay, const __half* __restrict__ xp,
    float* __restrict__ out, int N_) {
  int wid = threadIdx.x >> 6, lane = threadIdx.x & 63;
  int n = blockIdx.x * 4 + wid;
  if (n >= N_) return;
  int start = offs[n], len = count[n];
  if (len == 0) return;  // out keeps residual
  int h = lane >> 4;  // features 2*lane, 2*lane+1 -> head (2*lane)>>5 = lane>>4
  float2 acc = make_float2(0.f, 0.f);
  float se = 0.f;
#pragma unroll 8
  for (int i = 0; i < len; i++) {
    v4i p = __builtin_nontemporal_load(pay + start + i);  // uniform -> broadcast
    unsigned hw = (h < 2) ? (unsigned)p.y : (unsigned)p.z;
    unsigned bits = (h & 1) ? (hw >> 16) : (hw & 0xffffu);
    float ev = __half2float(__ushort_as_half((unsigned short)bits));
    const __half2* xr = (const __half2*)(xp + (size_t)p.x * HF);
    float2 xv = __half22float2(xr[lane]);  // random row: keep in L2
    acc.x += ev * xv.x;
    acc.y += ev * xv.y;
    se += ev;
  }
  float r = 1.f / se;
  size_t oi = (size_t)n * 64 + lane;
  v2f o = __builtin_nontemporal_load((const v2f*)out + oi);
  o.x += acc.x * r;
  o.y += acc.y * r;
  __builtin_nontemporal_store(o, (v2f*)out + oi);
}

extern "C" void kernel_launch(void* const* d_in, const int* in_sizes, int n_in,
                              void* d_out, int out_size, void* d_ws, size_t ws_size,
                              hipStream_t stream) {
  const float* x      = (const float*)d_in[0];
  const int*   ei     = (const int*)  d_in[1];
  const float* ea     = (const float*)d_in[2];
  const float* W_lin  = (const float*)d_in[3];
  const float* w_s    = (const float*)d_in[4];
  const float* b_s    = (const float*)d_in[5];
  const float* w_t    = (const float*)d_in[6];
  const float* b_t    = (const float*)d_in[7];
  const float* W_edge = (const float*)d_in[8];
  const float* w_e    = (const float*)d_in[9];
  const float* b_e    = (const float*)d_in[10];
  const float* W_res  = (const float*)d_in[11];
  const float* bias   = (const float*)d_in[12];
  int N_ = in_sizes[0] / IN_F;
  int E_ = in_sizes[1] / 2;
  float* out = (float*)d_out;

  // ws layout (~39.3 MB; 47.0 MB passed in rounds 3/4):
  // xp[N*128] f16 | pay[E] int4 | a_s[N*4] f32 | a_t[N*4] f32 |
  // count[N] | offs[N] | cursor[N] | bsum[64]
  __half* xp    = (__half*)d_ws;
  v4i*    pay   = (v4i*)(xp + (size_t)N_ * HF);
  float*  a_s   = (float*)(pay + E_);
  float*  a_t   = a_s + (size_t)N_ * 4;
  int*    count = (int*)(a_t + (size_t)N_ * 4);
  int*    offs  = count + N_;
  int*    cursor= offs + N_;
  int*    bsum  = cursor + N_;

  int NB = (N_ + 31) / 32;        // projection blocks
  int CB = (E_ + 127) / 128;      // histogram blocks
  int nb = (N_ + 1023) / 1024;    // scan chunks (49 for N=50000, must be <= 64)

  hipMemsetAsync(count, 0, (size_t)N_ * sizeof(int), stream);
  k_node_count<<<NB + CB, 128, 0, stream>>>(
      x, W_lin, W_res, bias, w_s, w_t, b_s, b_t, ei, xp, a_s, a_t, out, count,
      N_, E_, NB);
  k_scan1<<<nb, 256, 0, stream>>>(count, offs, bsum, N_);
  k_scan2<<<1, 64, 0, stream>>>(bsum, nb);
  k_scan3<<<nb, 256, 0, stream>>>(offs, bsum, cursor, N_);
  k_edge_sort<<<(E_ + 255) / 256, 256, 0, stream>>>(
      ei, ea, W_edge, w_e, b_e, a_s, a_t, cursor, pay, E_);
  k_gather<<<(N_ + 3) / 4, 256, 0, stream>>>(offs, count, pay, xp, out, N_);
}